// Round 11
// baseline (88.318 us; speedup 1.0000x reference)
//
#include <hip/hip_runtime.h>
#include <hip/hip_bf16.h>

// Problem constants
#define NA 32      // agents per graph
#define NACT 64    // actions
#define NIN 128    // in_dim
#define NOUT 128   // out_dim
#define NB 256     // graphs
// Inputs f32. Outputs f32: obs_final [8192,32,192] then w_out [8192,32,1].
//
// Structure (round 11): balance the obs-copy stream across both dispatches.
//   K1: 256 qk blocks + 4352 obs-copy blocks (rows 0..4351), interleaved 1:17.
//       qk compute (~10-12 us) hides under ~72 MB of write stream.
//   K2: 2048 z_mix blocks + 3840 obs-copy blocks (rows 4352..8191),
//       interleaved 8:15 -> balanced read+write mixed stream.

// ---------------------------------------------------------------------------
// shared device bodies
// ---------------------------------------------------------------------------
__device__ __forceinline__ void obs_copy_row(const float* __restrict__ obs,
                                             float* __restrict__ out,
                                             int gr, int tid)
{
    const int b = gr >> 5;
    const float4* so4 = reinterpret_cast<const float4*>(obs + (size_t)b * NA * NIN);
    float4* out4 = reinterpret_cast<float4*>(out) + (size_t)gr * 1536;
#pragma unroll
    for (int k = 0; k < 4; ++k) {
        const int m  = tid + 256 * k;   // 0..1023
        const int t2 = m >> 5;
        const int nn = m & 31;
        out4[t2 * 48 + nn] = so4[t2 * 32 + nn];
    }
}

// ---------------------------------------------------------------------------
// K1: 4608 blocks x 256. group = bid/18: member 0 -> qk for graph=group,
// members 1..17 -> obs-copy rows group*17 + (r-1)  (rows 0..4351).
// ---------------------------------------------------------------------------
__global__ __launch_bounds__(256) void k1_qk_obscopy(
    const float* __restrict__ h,
    const float* __restrict__ Wk, const float* __restrict__ bk,
    const float* __restrict__ Wq, const float* __restrict__ bq,
    const float* __restrict__ obs,
    float* __restrict__ out, float* __restrict__ w_out)
{
    __shared__ float sh[NA][NIN];         // 16 KB
    __shared__ float sK[NA][NOUT + 4];    // 16.5 KB
    __shared__ float sQ[NA][NOUT + 4];    // 16.5 KB

    const int bid = blockIdx.x;
    const int tid = threadIdx.x;
    const int grp = bid / 18;
    const int r   = bid - grp * 18;

    if (r != 0) {
        obs_copy_row(obs, out, grp * 17 + (r - 1), tid);
        return;
    }

    // ---- qk block for graph g
    const int g = grp;

    {
        const float4* hs = reinterpret_cast<const float4*>(h + (size_t)g * NA * NIN);
        float4* shl = reinterpret_cast<float4*>(&sh[0][0]);
#pragma unroll
        for (int k = 0; k < 4; ++k) { const int m = tid + 256 * k; shl[m] = hs[m]; }
    }
    __syncthreads();

    // projection: txg = tid&31 (4 out-dims), ty = tid>>5 (4 nodes)
    {
        const int txg = tid & 31;
        const int ty  = tid >> 5;
        float4 kacc[4], qacc[4];
        const float4 bk4 = *reinterpret_cast<const float4*>(bk + txg * 4);
        const float4 bq4 = *reinterpret_cast<const float4*>(bq + txg * 4);
#pragma unroll
        for (int s = 0; s < 4; ++s) { kacc[s] = bk4; qacc[s] = bq4; }

        for (int rr4 = 0; rr4 < NIN; rr4 += 4) {
            float4 wk[4], wq[4];
#pragma unroll
            for (int rr = 0; rr < 4; ++rr) {
                wk[rr] = *reinterpret_cast<const float4*>(Wk + (size_t)(rr4 + rr) * NOUT + txg * 4);
                wq[rr] = *reinterpret_cast<const float4*>(Wq + (size_t)(rr4 + rr) * NOUT + txg * 4);
            }
#pragma unroll
            for (int s = 0; s < 4; ++s) {
                const float4 hv = *reinterpret_cast<const float4*>(&sh[ty * 4 + s][rr4]);
                kacc[s].x = fmaf(hv.x, wk[0].x, fmaf(hv.y, wk[1].x, fmaf(hv.z, wk[2].x, fmaf(hv.w, wk[3].x, kacc[s].x))));
                kacc[s].y = fmaf(hv.x, wk[0].y, fmaf(hv.y, wk[1].y, fmaf(hv.z, wk[2].y, fmaf(hv.w, wk[3].y, kacc[s].y))));
                kacc[s].z = fmaf(hv.x, wk[0].z, fmaf(hv.y, wk[1].z, fmaf(hv.z, wk[2].z, fmaf(hv.w, wk[3].z, kacc[s].z))));
                kacc[s].w = fmaf(hv.x, wk[0].w, fmaf(hv.y, wk[1].w, fmaf(hv.z, wk[2].w, fmaf(hv.w, wk[3].w, kacc[s].w))));
                qacc[s].x = fmaf(hv.x, wq[0].x, fmaf(hv.y, wq[1].x, fmaf(hv.z, wq[2].x, fmaf(hv.w, wq[3].x, qacc[s].x))));
                qacc[s].y = fmaf(hv.x, wq[0].y, fmaf(hv.y, wq[1].y, fmaf(hv.z, wq[2].y, fmaf(hv.w, wq[3].y, qacc[s].y))));
                qacc[s].z = fmaf(hv.x, wq[0].z, fmaf(hv.y, wq[1].z, fmaf(hv.z, wq[2].z, fmaf(hv.w, wq[3].z, qacc[s].z))));
                qacc[s].w = fmaf(hv.x, wq[0].w, fmaf(hv.y, wq[1].w, fmaf(hv.z, wq[2].w, fmaf(hv.w, wq[3].w, qacc[s].w))));
            }
        }
#pragma unroll
        for (int s = 0; s < 4; ++s) {
            *reinterpret_cast<float4*>(&sK[ty * 4 + s][txg * 4]) = kacc[s];
            *reinterpret_cast<float4*>(&sQ[ty * 4 + s][txg * 4]) = qacc[s];
        }
    }
    __syncthreads();

    // scores + softmax: i = tid>>3 (dst row), jg = tid&7 (4 src j's)
    {
        const int i  = tid >> 3;
        const int jg = tid & 7;
        float sc[4] = {0.f, 0.f, 0.f, 0.f};
        for (int rr4 = 0; rr4 < NOUT; rr4 += 4) {
            const float4 qv = *reinterpret_cast<const float4*>(&sQ[i][rr4]);
#pragma unroll
            for (int jj = 0; jj < 4; ++jj) {
                const float4 kv = *reinterpret_cast<const float4*>(&sK[jg * 4 + jj][rr4]);
                sc[jj] = fmaf(qv.x, kv.x, fmaf(qv.y, kv.y, fmaf(qv.z, kv.z, fmaf(qv.w, kv.w, sc[jj]))));
            }
        }
#pragma unroll
        for (int jj = 0; jj < 4; ++jj) sc[jj] *= 0.08838834764831845f;  // 1/sqrt(128)

        float m = fmaxf(fmaxf(sc[0], sc[1]), fmaxf(sc[2], sc[3]));
        m = fmaxf(m, __shfl_xor(m, 1));
        m = fmaxf(m, __shfl_xor(m, 2));
        m = fmaxf(m, __shfl_xor(m, 4));
        float e[4], ssum;
#pragma unroll
        for (int jj = 0; jj < 4; ++jj) e[jj] = __expf(sc[jj] - m);
        ssum = e[0] + e[1] + e[2] + e[3];
        ssum += __shfl_xor(ssum, 1);
        ssum += __shfl_xor(ssum, 2);
        ssum += __shfl_xor(ssum, 4);
        const float inv = 1.0f / ssum;

        *reinterpret_cast<float4*>(w_out + ((size_t)g * NA + i) * NA + jg * 4) =
            make_float4(e[0] * inv, e[1] * inv, e[2] * inv, e[3] * inv);
    }
}

// ---------------------------------------------------------------------------
// K2: 5888 blocks x 256. group = bid/23: members 0..7 -> z_mix block
// zidx = group*8 + r (4 dst rows each); members 8..22 -> obs-copy rows
// 4352 + group*15 + (r-8)  (rows 4352..8191).
// ---------------------------------------------------------------------------
__global__ __launch_bounds__(256) void k2_zmix_obscopy(
    const float* __restrict__ policies, const float* __restrict__ actions,
    const float* __restrict__ obs, const float* __restrict__ noise,
    const float* __restrict__ w_in, float* __restrict__ out)
{
    __shared__ float spi[NA][NACT];   // 8 KB
    __shared__ float sac[NA][NACT];   // 8 KB
    __shared__ float sww[4][NA];      // 512 B

    const int bid = blockIdx.x;
    const int tid = threadIdx.x;
    const int grp = bid / 23;
    const int r   = bid - grp * 23;

    if (r >= 8) {
        obs_copy_row(obs, out, 4352 + grp * 15 + (r - 8), tid);
        return;
    }

    const int zidx = grp * 8 + r;     // 0..2047
    const int b    = zidx >> 3;       // graph

    {
        const float4* ps = reinterpret_cast<const float4*>(policies + (size_t)b * 2048);
        const float4* as = reinterpret_cast<const float4*>(actions  + (size_t)b * 2048);
        float4* pd = reinterpret_cast<float4*>(&spi[0][0]);
        float4* ad = reinterpret_cast<float4*>(&sac[0][0]);
        pd[tid] = ps[tid]; pd[tid + 256] = ps[tid + 256];
        ad[tid] = as[tid]; ad[tid + 256] = as[tid + 256];
        if (tid < 128) sww[tid >> 5][tid & 31] = w_in[(size_t)zidx * 128 + tid];
    }
    __syncthreads();

    const int wv   = tid >> 6;    // wave -> dst row
    const int lane = tid & 63;
    const int qq   = lane >> 4;   // t-quarter
    const int cg   = lane & 15;   // col group (4 floats)
    const int c0   = cg * 4;
    const size_t gr = (size_t)zidx * 4 + wv;   // = b*32 + i

    float4* out4 = reinterpret_cast<float4*>(out) + gr * 1536;

    float S0 = 0.f, S1 = 0.f, S2 = 0.f, S3 = 0.f;
    float y[8][4];
    const float* nzb = noise + (gr * 32 + qq * 8) * 64 + c0;
#pragma unroll
    for (int tt = 0; tt < 8; ++tt) {
        const int t = qq * 8 + tt;
        const float wt = sww[wv][t];
        const float4 p4 = *reinterpret_cast<const float4*>(&spi[t][c0]);
        const float4 a4 = *reinterpret_cast<const float4*>(&sac[t][c0]);
        const float4 n4 = *reinterpret_cast<const float4*>(nzb + tt * 64);
        float z;
        z = fmaf(wt, a4.x - p4.x, p4.x) + n4.x; S0 += z; y[tt][0] = p4.x - z;
        z = fmaf(wt, a4.y - p4.y, p4.y) + n4.y; S1 += z; y[tt][1] = p4.y - z;
        z = fmaf(wt, a4.z - p4.z, p4.z) + n4.z; S2 += z; y[tt][2] = p4.z - z;
        z = fmaf(wt, a4.w - p4.w, p4.w) + n4.w; S3 += z; y[tt][3] = p4.w - z;
    }
    S0 += __shfl_xor(S0, 16); S0 += __shfl_xor(S0, 32);
    S1 += __shfl_xor(S1, 16); S1 += __shfl_xor(S1, 32);
    S2 += __shfl_xor(S2, 16); S2 += __shfl_xor(S2, 32);
    S3 += __shfl_xor(S3, 16); S3 += __shfl_xor(S3, 32);

#pragma unroll
    for (int tt = 0; tt < 8; ++tt) {
        const int t = qq * 8 + tt;
        float4 o;
        o.x = (S0 + y[tt][0]) * (1.0f / NA);
        o.y = (S1 + y[tt][1]) * (1.0f / NA);
        o.z = (S2 + y[tt][2]) * (1.0f / NA);
        o.w = (S3 + y[tt][3]) * (1.0f / NA);
        out4[t * 48 + 32 + cg] = o;
    }
}

extern "C" void kernel_launch(void* const* d_in, const int* in_sizes, int n_in,
                              void* d_out, int out_size, void* d_ws, size_t ws_size,
                              hipStream_t stream) {
    const float* h        = (const float*)d_in[0];
    const float* policies = (const float*)d_in[1];
    const float* actions  = (const float*)d_in[2];
    const float* obs_proc = (const float*)d_in[3];
    const float* noise    = (const float*)d_in[4];
    const float* Wk       = (const float*)d_in[5];
    const float* bk       = (const float*)d_in[6];
    const float* Wq       = (const float*)d_in[7];
    const float* bq       = (const float*)d_in[8];

    float* out = (float*)d_out;
    float* obs_final = out;                                      // [8192,32,192]
    float* w_out = out + (size_t)NB * NA * NA * (NIN + NACT);    // [8192,32,1]

    k1_qk_obscopy<<<256 * 18, 256, 0, stream>>>(h, Wk, bk, Wq, bq, obs_proc,
                                                obs_final, w_out);
    k2_zmix_obscopy<<<256 * 23, 256, 0, stream>>>(policies, actions, obs_proc,
                                                  noise, w_out, obs_final);
}

// Round 13
// 83.897 us; speedup vs baseline: 1.0527x; 1.0527x over previous
//
#include <hip/hip_runtime.h>
#include <hip/hip_bf16.h>

// Problem constants
#define NA 32      // agents per graph
#define NACT 64    // actions
#define NIN 128    // in_dim
#define NOUT 128   // out_dim
#define NB 256     // graphs
// Inputs f32. Outputs f32: obs_final [8192,32,192] then w_out [8192,32,1].
//
// Round 12 structure (resubmitted after infra failure):
//   K1: qk only (256 blocks x 256 thr) -> w_out.            (~10 us serial)
//   K2: uniform blocks, NO LDS, NO barriers. 2048 blocks x 256 thr;
//       wave = one dst row: z_mix (pi/act/w from L2, noise from HBM,
//       shfl-only reduction) + that row's obs copy. Max occupancy,
//       homogeneous streaming.

// ---------------------------------------------------------------------------
// K1: per-graph QK projection + softmax -> w (f32). grid=256, block=256.
// ---------------------------------------------------------------------------
__global__ __launch_bounds__(256) void k1_qk(
    const float* __restrict__ h,
    const float* __restrict__ Wk, const float* __restrict__ bk,
    const float* __restrict__ Wq, const float* __restrict__ bq,
    float* __restrict__ w_out)
{
    __shared__ float sh[NA][NIN];         // 16 KB
    __shared__ float sK[NA][NOUT + 4];    // 16.5 KB
    __shared__ float sQ[NA][NOUT + 4];    // 16.5 KB

    const int g   = blockIdx.x;
    const int tid = threadIdx.x;

    {
        const float4* hs = reinterpret_cast<const float4*>(h + (size_t)g * NA * NIN);
        float4* shl = reinterpret_cast<float4*>(&sh[0][0]);
#pragma unroll
        for (int k = 0; k < 4; ++k) { const int m = tid + 256 * k; shl[m] = hs[m]; }
    }
    __syncthreads();

    // projection: txg = tid&31 (4 out-dims), ty = tid>>5 (4 nodes)
    {
        const int txg = tid & 31;
        const int ty  = tid >> 5;
        float4 kacc[4], qacc[4];
        const float4 bk4 = *reinterpret_cast<const float4*>(bk + txg * 4);
        const float4 bq4 = *reinterpret_cast<const float4*>(bq + txg * 4);
#pragma unroll
        for (int s = 0; s < 4; ++s) { kacc[s] = bk4; qacc[s] = bq4; }

        for (int rr4 = 0; rr4 < NIN; rr4 += 4) {
            float4 wk[4], wq[4];
#pragma unroll
            for (int rr = 0; rr < 4; ++rr) {
                wk[rr] = *reinterpret_cast<const float4*>(Wk + (size_t)(rr4 + rr) * NOUT + txg * 4);
                wq[rr] = *reinterpret_cast<const float4*>(Wq + (size_t)(rr4 + rr) * NOUT + txg * 4);
            }
#pragma unroll
            for (int s = 0; s < 4; ++s) {
                const float4 hv = *reinterpret_cast<const float4*>(&sh[ty * 4 + s][rr4]);
                kacc[s].x = fmaf(hv.x, wk[0].x, fmaf(hv.y, wk[1].x, fmaf(hv.z, wk[2].x, fmaf(hv.w, wk[3].x, kacc[s].x))));
                kacc[s].y = fmaf(hv.x, wk[0].y, fmaf(hv.y, wk[1].y, fmaf(hv.z, wk[2].y, fmaf(hv.w, wk[3].y, kacc[s].y))));
                kacc[s].z = fmaf(hv.x, wk[0].z, fmaf(hv.y, wk[1].z, fmaf(hv.z, wk[2].z, fmaf(hv.w, wk[3].z, kacc[s].z))));
                kacc[s].w = fmaf(hv.x, wk[0].w, fmaf(hv.y, wk[1].w, fmaf(hv.z, wk[2].w, fmaf(hv.w, wk[3].w, kacc[s].w))));
                qacc[s].x = fmaf(hv.x, wq[0].x, fmaf(hv.y, wq[1].x, fmaf(hv.z, wq[2].x, fmaf(hv.w, wq[3].x, qacc[s].x))));
                qacc[s].y = fmaf(hv.x, wq[0].y, fmaf(hv.y, wq[1].y, fmaf(hv.z, wq[2].y, fmaf(hv.w, wq[3].y, qacc[s].y))));
                qacc[s].z = fmaf(hv.x, wq[0].z, fmaf(hv.y, wq[1].z, fmaf(hv.z, wq[2].z, fmaf(hv.w, wq[3].z, qacc[s].z))));
                qacc[s].w = fmaf(hv.x, wq[0].w, fmaf(hv.y, wq[1].w, fmaf(hv.z, wq[2].w, fmaf(hv.w, wq[3].w, qacc[s].w))));
            }
        }
#pragma unroll
        for (int s = 0; s < 4; ++s) {
            *reinterpret_cast<float4*>(&sK[ty * 4 + s][txg * 4]) = kacc[s];
            *reinterpret_cast<float4*>(&sQ[ty * 4 + s][txg * 4]) = qacc[s];
        }
    }
    __syncthreads();

    // scores + softmax: i = tid>>3 (dst row), jg = tid&7 (4 src j's)
    {
        const int i  = tid >> 3;
        const int jg = tid & 7;
        float sc[4] = {0.f, 0.f, 0.f, 0.f};
        for (int rr4 = 0; rr4 < NOUT; rr4 += 4) {
            const float4 qv = *reinterpret_cast<const float4*>(&sQ[i][rr4]);
#pragma unroll
            for (int jj = 0; jj < 4; ++jj) {
                const float4 kv = *reinterpret_cast<const float4*>(&sK[jg * 4 + jj][rr4]);
                sc[jj] = fmaf(qv.x, kv.x, fmaf(qv.y, kv.y, fmaf(qv.z, kv.z, fmaf(qv.w, kv.w, sc[jj]))));
            }
        }
#pragma unroll
        for (int jj = 0; jj < 4; ++jj) sc[jj] *= 0.08838834764831845f;  // 1/sqrt(128)

        float m = fmaxf(fmaxf(sc[0], sc[1]), fmaxf(sc[2], sc[3]));
        m = fmaxf(m, __shfl_xor(m, 1));
        m = fmaxf(m, __shfl_xor(m, 2));
        m = fmaxf(m, __shfl_xor(m, 4));
        float e[4], ssum;
#pragma unroll
        for (int jj = 0; jj < 4; ++jj) e[jj] = __expf(sc[jj] - m);
        ssum = e[0] + e[1] + e[2] + e[3];
        ssum += __shfl_xor(ssum, 1);
        ssum += __shfl_xor(ssum, 2);
        ssum += __shfl_xor(ssum, 4);
        const float inv = 1.0f / ssum;

        *reinterpret_cast<float4*>(w_out + ((size_t)g * NA + i) * NA + jg * 4) =
            make_float4(e[0] * inv, e[1] * inv, e[2] * inv, e[3] * inv);
    }
}

// ---------------------------------------------------------------------------
// K2: uniform full-row blocks. No LDS, no barriers. grid=2048, block=256.
// Wave wv owns dst row gr = blk*4 + wv. Lane: qq=lane>>4 (8 t's), cg=lane&15.
// ---------------------------------------------------------------------------
__global__ __launch_bounds__(256) void k2_row(
    const float* __restrict__ policies, const float* __restrict__ actions,
    const float* __restrict__ obs, const float* __restrict__ noise,
    const float* __restrict__ w_in, float* __restrict__ out)
{
    const int tid  = threadIdx.x;
    const int wv   = tid >> 6;
    const int lane = tid & 63;
    const int qq   = lane >> 4;
    const int cg   = lane & 15;
    const int c0   = cg * 4;

    const size_t gr = (size_t)blockIdx.x * 4 + wv;   // dst row = b*32 + i
    const int b = (int)(gr >> 5);

    const float* pig = policies + (size_t)b * 2048;
    const float* acg = actions  + (size_t)b * 2048;
    const float* wrow = w_in + gr * NA;
    const float* nzb  = noise + gr * 2048 + (size_t)qq * 8 * 64 + c0;

    float4* out4 = reinterpret_cast<float4*>(out) + gr * 1536;
    const float4* so4 = reinterpret_cast<const float4*>(obs + (size_t)b * NA * NIN);

    // ---- z pass: 8 t's per lane, everything from L2 (pi/act/w) + HBM (noise)
    float S0 = 0.f, S1 = 0.f, S2 = 0.f, S3 = 0.f;
    float y[8][4];
#pragma unroll
    for (int tt = 0; tt < 8; ++tt) {
        const int t = qq * 8 + tt;
        const float wt = wrow[t];
        const float4 p4 = *reinterpret_cast<const float4*>(pig + t * 64 + c0);
        const float4 a4 = *reinterpret_cast<const float4*>(acg + t * 64 + c0);
        const float4 n4 = *reinterpret_cast<const float4*>(nzb + tt * 64);
        float z;
        z = fmaf(wt, a4.x - p4.x, p4.x) + n4.x; S0 += z; y[tt][0] = p4.x - z;
        z = fmaf(wt, a4.y - p4.y, p4.y) + n4.y; S1 += z; y[tt][1] = p4.y - z;
        z = fmaf(wt, a4.z - p4.z, p4.z) + n4.z; S2 += z; y[tt][2] = p4.z - z;
        z = fmaf(wt, a4.w - p4.w, p4.w) + n4.w; S3 += z; y[tt][3] = p4.w - z;
    }
    S0 += __shfl_xor(S0, 16); S0 += __shfl_xor(S0, 32);
    S1 += __shfl_xor(S1, 16); S1 += __shfl_xor(S1, 32);
    S2 += __shfl_xor(S2, 16); S2 += __shfl_xor(S2, 32);
    S3 += __shfl_xor(S3, 16); S3 += __shfl_xor(S3, 32);

#pragma unroll
    for (int tt = 0; tt < 8; ++tt) {
        const int t = qq * 8 + tt;
        float4 o;
        o.x = (S0 + y[tt][0]) * (1.0f / NA);
        o.y = (S1 + y[tt][1]) * (1.0f / NA);
        o.z = (S2 + y[tt][2]) * (1.0f / NA);
        o.w = (S3 + y[tt][3]) * (1.0f / NA);
        out4[t * 48 + 32 + cg] = o;
    }

    // ---- obs copy for this row: 16 float4 per lane (L2-hot after 1st touch)
#pragma unroll
    for (int k = 0; k < 16; ++k) {
        const int idx = lane + 64 * k;     // 0..1023
        const int t2  = idx >> 5;
        const int nn  = idx & 31;
        out4[t2 * 48 + nn] = so4[t2 * 32 + nn];
    }
}

extern "C" void kernel_launch(void* const* d_in, const int* in_sizes, int n_in,
                              void* d_out, int out_size, void* d_ws, size_t ws_size,
                              hipStream_t stream) {
    const float* h        = (const float*)d_in[0];
    const float* policies = (const float*)d_in[1];
    const float* actions  = (const float*)d_in[2];
    const float* obs_proc = (const float*)d_in[3];
    const float* noise    = (const float*)d_in[4];
    const float* Wk       = (const float*)d_in[5];
    const float* bk       = (const float*)d_in[6];
    const float* Wq       = (const float*)d_in[7];
    const float* bq       = (const float*)d_in[8];

    float* out = (float*)d_out;
    float* obs_final = out;                                      // [8192,32,192]
    float* w_out = out + (size_t)NB * NA * NA * (NIN + NACT);    // [8192,32,1]

    k1_qk<<<NB, 256, 0, stream>>>(h, Wk, bk, Wq, bq, w_out);
    k2_row<<<NB * NA / 4, 256, 0, stream>>>(policies, actions, obs_proc, noise,
                                            w_out, obs_final);
}

// Round 14
// 60.990 us; speedup vs baseline: 1.4481x; 1.3756x over previous
//
#include <hip/hip_runtime.h>
#include <hip/hip_bf16.h>

// Problem constants
#define NA 32      // agents per graph
#define NACT 64    // actions
#define NIN 128    // in_dim
#define NOUT 128   // out_dim
#define NB 256     // graphs
// Inputs f32. Outputs f32: obs_final [8192,32,192] then w_out [8192,32,1].
//
// Round 14 = round-10 structure (best: 64.0 us) + pipelined K2.
//   K1: 8448 blocks: [0,256) qk -> w_out; [256,8448) obs-copy rows (134 MB).
//   K2: 1024 blocks x 256 thr; 8 rows/block; pi/act/w staged in LDS;
//       wave owns 2 rows, issues all 16 noise loads up front (row-1 loads
//       in flight under row-0 compute+stores).

// ---------------------------------------------------------------------------
// K1: qk blocks + obs-copy blocks (verbatim round-10 body).
// ---------------------------------------------------------------------------
__global__ __launch_bounds__(256) void k1_qk_obscopy(
    const float* __restrict__ h,
    const float* __restrict__ Wk, const float* __restrict__ bk,
    const float* __restrict__ Wq, const float* __restrict__ bq,
    const float* __restrict__ obs,
    float* __restrict__ out, float* __restrict__ w_out)
{
    __shared__ float sh[NA][NIN];         // 16 KB
    __shared__ float sK[NA][NOUT + 4];    // 16.5 KB
    __shared__ float sQ[NA][NOUT + 4];    // 16.5 KB

    const int bid = blockIdx.x;
    const int tid = threadIdx.x;

    if (bid >= NB) {
        // obs-copy block: dst row gr = bid-256
        const int gr = bid - NB;
        const int b  = gr >> 5;
        const float4* so4 = reinterpret_cast<const float4*>(obs + (size_t)b * NA * NIN);
        float4* out4 = reinterpret_cast<float4*>(out) + (size_t)gr * 1536;
#pragma unroll
        for (int k = 0; k < 4; ++k) {
            const int m  = tid + 256 * k;   // 0..1023
            const int t2 = m >> 5;
            const int nn = m & 31;
            out4[t2 * 48 + nn] = so4[t2 * 32 + nn];
        }
        return;
    }

    // ---- qk block for graph g
    const int g = bid;

    {
        const float4* hs = reinterpret_cast<const float4*>(h + (size_t)g * NA * NIN);
        float4* shl = reinterpret_cast<float4*>(&sh[0][0]);
#pragma unroll
        for (int k = 0; k < 4; ++k) { const int m = tid + 256 * k; shl[m] = hs[m]; }
    }
    __syncthreads();

    // projection: txg = tid&31 (4 out-dims), ty = tid>>5 (4 nodes)
    {
        const int txg = tid & 31;
        const int ty  = tid >> 5;
        float4 kacc[4], qacc[4];
        const float4 bk4 = *reinterpret_cast<const float4*>(bk + txg * 4);
        const float4 bq4 = *reinterpret_cast<const float4*>(bq + txg * 4);
#pragma unroll
        for (int s = 0; s < 4; ++s) { kacc[s] = bk4; qacc[s] = bq4; }

        for (int rr4 = 0; rr4 < NIN; rr4 += 4) {
            float4 wk[4], wq[4];
#pragma unroll
            for (int rr = 0; rr < 4; ++rr) {
                wk[rr] = *reinterpret_cast<const float4*>(Wk + (size_t)(rr4 + rr) * NOUT + txg * 4);
                wq[rr] = *reinterpret_cast<const float4*>(Wq + (size_t)(rr4 + rr) * NOUT + txg * 4);
            }
#pragma unroll
            for (int s = 0; s < 4; ++s) {
                const float4 hv = *reinterpret_cast<const float4*>(&sh[ty * 4 + s][rr4]);
                kacc[s].x = fmaf(hv.x, wk[0].x, fmaf(hv.y, wk[1].x, fmaf(hv.z, wk[2].x, fmaf(hv.w, wk[3].x, kacc[s].x))));
                kacc[s].y = fmaf(hv.x, wk[0].y, fmaf(hv.y, wk[1].y, fmaf(hv.z, wk[2].y, fmaf(hv.w, wk[3].y, kacc[s].y))));
                kacc[s].z = fmaf(hv.x, wk[0].z, fmaf(hv.y, wk[1].z, fmaf(hv.z, wk[2].z, fmaf(hv.w, wk[3].z, kacc[s].z))));
                kacc[s].w = fmaf(hv.x, wk[0].w, fmaf(hv.y, wk[1].w, fmaf(hv.z, wk[2].w, fmaf(hv.w, wk[3].w, kacc[s].w))));
                qacc[s].x = fmaf(hv.x, wq[0].x, fmaf(hv.y, wq[1].x, fmaf(hv.z, wq[2].x, fmaf(hv.w, wq[3].x, qacc[s].x))));
                qacc[s].y = fmaf(hv.x, wq[0].y, fmaf(hv.y, wq[1].y, fmaf(hv.z, wq[2].y, fmaf(hv.w, wq[3].y, qacc[s].y))));
                qacc[s].z = fmaf(hv.x, wq[0].z, fmaf(hv.y, wq[1].z, fmaf(hv.z, wq[2].z, fmaf(hv.w, wq[3].z, qacc[s].z))));
                qacc[s].w = fmaf(hv.x, wq[0].w, fmaf(hv.y, wq[1].w, fmaf(hv.z, wq[2].w, fmaf(hv.w, wq[3].w, qacc[s].w))));
            }
        }
#pragma unroll
        for (int s = 0; s < 4; ++s) {
            *reinterpret_cast<float4*>(&sK[ty * 4 + s][txg * 4]) = kacc[s];
            *reinterpret_cast<float4*>(&sQ[ty * 4 + s][txg * 4]) = qacc[s];
        }
    }
    __syncthreads();

    // scores + softmax: i = tid>>3 (dst row), jg = tid&7 (4 src j's)
    {
        const int i  = tid >> 3;
        const int jg = tid & 7;
        float sc[4] = {0.f, 0.f, 0.f, 0.f};
        for (int rr4 = 0; rr4 < NOUT; rr4 += 4) {
            const float4 qv = *reinterpret_cast<const float4*>(&sQ[i][rr4]);
#pragma unroll
            for (int jj = 0; jj < 4; ++jj) {
                const float4 kv = *reinterpret_cast<const float4*>(&sK[jg * 4 + jj][rr4]);
                sc[jj] = fmaf(qv.x, kv.x, fmaf(qv.y, kv.y, fmaf(qv.z, kv.z, fmaf(qv.w, kv.w, sc[jj]))));
            }
        }
#pragma unroll
        for (int jj = 0; jj < 4; ++jj) sc[jj] *= 0.08838834764831845f;  // 1/sqrt(128)

        float m = fmaxf(fmaxf(sc[0], sc[1]), fmaxf(sc[2], sc[3]));
        m = fmaxf(m, __shfl_xor(m, 1));
        m = fmaxf(m, __shfl_xor(m, 2));
        m = fmaxf(m, __shfl_xor(m, 4));
        float e[4], ssum;
#pragma unroll
        for (int jj = 0; jj < 4; ++jj) e[jj] = __expf(sc[jj] - m);
        ssum = e[0] + e[1] + e[2] + e[3];
        ssum += __shfl_xor(ssum, 1);
        ssum += __shfl_xor(ssum, 2);
        ssum += __shfl_xor(ssum, 4);
        const float inv = 1.0f / ssum;

        *reinterpret_cast<float4*>(w_out + ((size_t)g * NA + i) * NA + jg * 4) =
            make_float4(e[0] * inv, e[1] * inv, e[2] * inv, e[3] * inv);
    }
}

// ---------------------------------------------------------------------------
// K2: pipelined z_mix. grid=1024, block=256 (4 waves). 8 rows/block (one
// graph quarter... rows blk*8..blk*8+7, graph = blk>>2). Wave wv owns rows
// lr0 = wv*2 and lr0+1; issues BOTH rows' noise loads up front.
// ---------------------------------------------------------------------------
__global__ __launch_bounds__(256) void k2_zmix(
    const float* __restrict__ policies, const float* __restrict__ actions,
    const float* __restrict__ noise, const float* __restrict__ w_in,
    float* __restrict__ out)
{
    __shared__ float spi[2048];   // 8 KB
    __shared__ float sac[2048];   // 8 KB
    __shared__ float sww[256];    // 1 KB  (8 rows x 32 w's)

    const int blk = blockIdx.x;   // 0..1023
    const int b   = blk >> 2;     // graph
    const int tid = threadIdx.x;

    {
        const float4* ps = reinterpret_cast<const float4*>(policies + (size_t)b * 2048);
        const float4* as = reinterpret_cast<const float4*>(actions  + (size_t)b * 2048);
        float4* pd = reinterpret_cast<float4*>(spi);
        float4* ad = reinterpret_cast<float4*>(sac);
        pd[tid] = ps[tid]; pd[tid + 256] = ps[tid + 256];
        ad[tid] = as[tid]; ad[tid + 256] = as[tid + 256];
        sww[tid] = w_in[(size_t)blk * 256 + tid];
    }
    __syncthreads();

    const int wv   = tid >> 6;
    const int lane = tid & 63;
    const int qq   = lane >> 4;   // t-octet 0..3
    const int cg   = lane & 15;   // col group (4 floats)
    const int c0   = cg * 4;
    const int lr0  = wv * 2;                    // local rows lr0, lr0+1
    const size_t r0 = (size_t)blk * 8 + lr0;    // global dst rows r0, r0+1

    // ---- issue ALL 16 noise loads (both rows) before any compute
    const float* nz0 = noise + r0 * 2048 + qq * 512 + c0;
    const float* nz1 = nz0 + 2048;
    float4 A[8], B[8];
#pragma unroll
    for (int tt = 0; tt < 8; ++tt) A[tt] = *reinterpret_cast<const float4*>(nz0 + tt * 64);
#pragma unroll
    for (int tt = 0; tt < 8; ++tt) B[tt] = *reinterpret_cast<const float4*>(nz1 + tt * 64);

    auto do_row = [&](const float4* BUF, int lr, size_t gr) {
        const float* wr = &sww[lr * 32];
        float S0 = 0.f, S1 = 0.f, S2 = 0.f, S3 = 0.f;
        float y[8][4];
#pragma unroll
        for (int tt = 0; tt < 8; ++tt) {
            const int t = qq * 8 + tt;
            const float wt = wr[t];
            const float4 p4 = *reinterpret_cast<const float4*>(&spi[t * 64 + c0]);
            const float4 a4 = *reinterpret_cast<const float4*>(&sac[t * 64 + c0]);
            const float4 n4 = BUF[tt];
            float z;
            z = fmaf(wt, a4.x - p4.x, p4.x) + n4.x; S0 += z; y[tt][0] = p4.x - z;
            z = fmaf(wt, a4.y - p4.y, p4.y) + n4.y; S1 += z; y[tt][1] = p4.y - z;
            z = fmaf(wt, a4.z - p4.z, p4.z) + n4.z; S2 += z; y[tt][2] = p4.z - z;
            z = fmaf(wt, a4.w - p4.w, p4.w) + n4.w; S3 += z; y[tt][3] = p4.w - z;
        }
        S0 += __shfl_xor(S0, 16); S0 += __shfl_xor(S0, 32);
        S1 += __shfl_xor(S1, 16); S1 += __shfl_xor(S1, 32);
        S2 += __shfl_xor(S2, 16); S2 += __shfl_xor(S2, 32);
        S3 += __shfl_xor(S3, 16); S3 += __shfl_xor(S3, 32);

        float4* out4 = reinterpret_cast<float4*>(out) + gr * 1536;
#pragma unroll
        for (int tt = 0; tt < 8; ++tt) {
            const int t = qq * 8 + tt;
            float4 o;
            o.x = (S0 + y[tt][0]) * (1.0f / NA);
            o.y = (S1 + y[tt][1]) * (1.0f / NA);
            o.z = (S2 + y[tt][2]) * (1.0f / NA);
            o.w = (S3 + y[tt][3]) * (1.0f / NA);
            out4[t * 48 + 32 + cg] = o;
        }
    };

    // row 0 compute waits only on A's 8 loads (B stays in flight)
    do_row(A, lr0, r0);
    do_row(B, lr0 + 1, r0 + 1);
}

extern "C" void kernel_launch(void* const* d_in, const int* in_sizes, int n_in,
                              void* d_out, int out_size, void* d_ws, size_t ws_size,
                              hipStream_t stream) {
    const float* h        = (const float*)d_in[0];
    const float* policies = (const float*)d_in[1];
    const float* actions  = (const float*)d_in[2];
    const float* obs_proc = (const float*)d_in[3];
    const float* noise    = (const float*)d_in[4];
    const float* Wk       = (const float*)d_in[5];
    const float* bk       = (const float*)d_in[6];
    const float* Wq       = (const float*)d_in[7];
    const float* bq       = (const float*)d_in[8];

    float* out = (float*)d_out;
    float* obs_final = out;                                      // [8192,32,192]
    float* w_out = out + (size_t)NB * NA * NA * (NIN + NACT);    // [8192,32,1]

    k1_qk_obscopy<<<NB + NB * NA, 256, 0, stream>>>(h, Wk, bk, Wq, bq, obs_proc,
                                                    obs_final, w_out);
    k2_zmix<<<1024, 256, 0, stream>>>(policies, actions, noise, w_out, obs_final);
}